// Round 1
// baseline (393.421 us; speedup 1.0000x reference)
//
#include <hip/hip_runtime.h>
#include <math.h>

#define N 4096
#define D 512
#define C 128
#define ALPHA 0.0005f

// ---------------------------------------------------------------------------
// prep: sq[i] = sum_k x[i,k]^2 ; dot0[i] = sum_k x[i,k]*x[0,k]
// ---------------------------------------------------------------------------
__global__ __launch_bounds__(256) void prep_kernel(const float* __restrict__ x,
                                                   float* __restrict__ sq,
                                                   float* __restrict__ dot0) {
    const int i = blockIdx.x;
    const int t = threadIdx.x;
    float s1 = 0.f, s2 = 0.f;
    for (int k = t; k < D; k += 256) {
        float v = x[(size_t)i * D + k];
        s1 += v * v;
        s2 += v * x[k];           // x[0,k]
    }
    for (int o = 32; o; o >>= 1) {
        s1 += __shfl_down(s1, o);
        s2 += __shfl_down(s2, o);
    }
    __shared__ float r1[4], r2[4];
    if ((t & 63) == 0) { r1[t >> 6] = s1; r2[t >> 6] = s2; }
    __syncthreads();
    if (t == 0) {
        sq[i]   = r1[0] + r1[1] + r1[2] + r1[3];
        dot0[i] = r2[0] + r2[1] + r2[2] + r2[3];
    }
}

// ---------------------------------------------------------------------------
// CE loss per row: logits = x_i @ W + b ; lossrow[i] = -(logit[y_i]-max-log(sum exp))
// one block (128 threads) per row; thread c owns logit c.
// ---------------------------------------------------------------------------
__global__ __launch_bounds__(128) void ce_kernel(const float* __restrict__ x,
                                                 const int* __restrict__ y,
                                                 const float* __restrict__ W,
                                                 const float* __restrict__ b,
                                                 float* __restrict__ lossrow) {
    __shared__ float xs[D];
    __shared__ float redmax[2];
    __shared__ float redsum[2];
    const int i = blockIdx.x;
    const int t = threadIdx.x;

    for (int k = t; k < D; k += 128) xs[k] = x[(size_t)i * D + k];
    __syncthreads();

    float acc = b[t];
#pragma unroll 8
    for (int k = 0; k < D; ++k) acc += xs[k] * W[k * C + t];

    // block max over 128 threads (2 waves)
    float m = acc;
    for (int o = 32; o; o >>= 1) m = fmaxf(m, __shfl_down(m, o));
    if ((t & 63) == 0) redmax[t >> 6] = m;
    __syncthreads();
    m = fmaxf(redmax[0], redmax[1]);

    float s = expf(acc - m);
    for (int o = 32; o; o >>= 1) s += __shfl_down(s, o);
    if ((t & 63) == 0) redsum[t >> 6] = s;
    __syncthreads();
    s = redsum[0] + redsum[1];

    if (t == y[i]) lossrow[i] = -(acc - m - logf(s));
}

// ---------------------------------------------------------------------------
// count: cnt[i] = #{ j not in {0,i} : d2[i,j] < d2[i,0] }
// comparison with sq_i cancelled:  sq[j] - 2*dot(x_i,x_j) < sq[0] - 2*dot0[i]
// 128x128 tile per 256-thread block, 8x8 register blocking, K-chunks of 8.
// ---------------------------------------------------------------------------
#define TI 128
#define KC 8

__global__ __launch_bounds__(256) void count_kernel(const float* __restrict__ x,
                                                    const float* __restrict__ sq,
                                                    const float* __restrict__ dot0,
                                                    unsigned* __restrict__ cnt) {
    __shared__ float As[KC][TI + 4];   // [k][i], row = 132 floats = 528 B (16B aligned)
    __shared__ float Bs[KC][TI + 4];   // [k][j]
    const int bi = (int)(blockIdx.x & 31) * TI;
    const int bj = (int)(blockIdx.x >> 5) * TI;
    const int t  = threadIdx.x;
    const int tx = t & 15;     // j-octet
    const int ty = t >> 4;     // i-octet
    const int lrow = t >> 1;        // staging row 0..127
    const int lk   = (t & 1) * 4;   // staging k quad

    float acc[8][8] = {};

    for (int kc = 0; kc < D; kc += KC) {
        float4 a = *(const float4*)(x + (size_t)(bi + lrow) * D + kc + lk);
        float4 bb = *(const float4*)(x + (size_t)(bj + lrow) * D + kc + lk);
        __syncthreads();   // previous-iteration LDS reads done
        As[lk + 0][lrow] = a.x;  As[lk + 1][lrow] = a.y;
        As[lk + 2][lrow] = a.z;  As[lk + 3][lrow] = a.w;
        Bs[lk + 0][lrow] = bb.x; Bs[lk + 1][lrow] = bb.y;
        Bs[lk + 2][lrow] = bb.z; Bs[lk + 3][lrow] = bb.w;
        __syncthreads();
#pragma unroll
        for (int kk = 0; kk < KC; ++kk) {
            float4 a0 = *(const float4*)&As[kk][ty * 8];
            float4 a1 = *(const float4*)&As[kk][ty * 8 + 4];
            float4 b0 = *(const float4*)&Bs[kk][tx * 8];
            float4 b1 = *(const float4*)&Bs[kk][tx * 8 + 4];
            float av[8] = {a0.x, a0.y, a0.z, a0.w, a1.x, a1.y, a1.z, a1.w};
            float bv[8] = {b0.x, b0.y, b0.z, b0.w, b1.x, b1.y, b1.z, b1.w};
#pragma unroll
            for (int r = 0; r < 8; ++r)
#pragma unroll
                for (int c = 0; c < 8; ++c)
                    acc[r][c] += av[r] * bv[c];
        }
    }

    const float sq0 = sq[0];
    unsigned cr[8];
#pragma unroll
    for (int r = 0; r < 8; ++r) {
        const int i = bi + ty * 8 + r;
        const float ti = sq0 - 2.0f * dot0[i];
        unsigned cc = 0;
#pragma unroll
        for (int c = 0; c < 8; ++c) {
            const int j = bj + tx * 8 + c;
            const float lhs = sq[j] - 2.0f * acc[r][c];
            if (lhs < ti && j != i && j != 0) ++cc;
        }
        cr[r] = cc;
    }
    // reduce the 16 j-octet partials of each row (contiguous 16 lanes) and atomically add
#pragma unroll
    for (int r = 0; r < 8; ++r) {
        unsigned v = cr[r];
        v += __shfl_down(v, 8, 16);
        v += __shfl_down(v, 4, 16);
        v += __shfl_down(v, 2, 16);
        v += __shfl_down(v, 1, 16);
        if (tx == 0 && v) atomicAdd(&cnt[bi + ty * 8 + r], v);
    }
}

// ---------------------------------------------------------------------------
// finalize: out = mean(lossrow) + ALPHA * sum_{i>0, y_i==y_0, cnt[i]<=1} ||Y_i - Y_0||
// double-precision block reduction (f32 accumulation of 4096 CE terms would
// random-walk to ~0.03 abs error; threshold is 0.0988).
// ---------------------------------------------------------------------------
__global__ __launch_bounds__(256) void final_kernel(const float* __restrict__ lossrow,
                                                    const unsigned* __restrict__ cnt,
                                                    const int* __restrict__ y,
                                                    const float* __restrict__ Y,
                                                    float* __restrict__ out) {
    const int t = threadIdx.x;
    const int y0 = y[0];
    double ls = 0.0, rs = 0.0;
    for (int i = t; i < N; i += 256) {
        ls += (double)lossrow[i];
        if (i > 0 && y[i] == y0 && cnt[i] <= 1u) {
            float d2 = 0.f;
            for (int c = 0; c < C; ++c) {
                float d = Y[(size_t)i * C + c] - Y[c];
                d2 += d * d;
            }
            rs += (double)sqrtf(fmaxf(d2, 0.f));
        }
    }
    for (int o = 32; o; o >>= 1) {
        ls += __shfl_down(ls, o);
        rs += __shfl_down(rs, o);
    }
    __shared__ double dl[4], dr[4];
    if ((t & 63) == 0) { dl[t >> 6] = ls; dr[t >> 6] = rs; }
    __syncthreads();
    if (t == 0) {
        double L = (dl[0] + dl[1] + dl[2] + dl[3]) / (double)N;
        double R = (dr[0] + dr[1] + dr[2] + dr[3]);
        out[0] = (float)(L + (double)ALPHA * R);
    }
}

// ---------------------------------------------------------------------------
extern "C" void kernel_launch(void* const* d_in, const int* in_sizes, int n_in,
                              void* d_out, int out_size, void* d_ws, size_t ws_size,
                              hipStream_t stream) {
    const float* x  = (const float*)d_in[0];   // (N, D)
    const int*   y  = (const int*)d_in[1];     // (N,)
    const float* Y  = (const float*)d_in[2];   // (N, C)
    const float* W  = (const float*)d_in[3];   // (D, C)
    const float* b  = (const float*)d_in[4];   // (C,)
    float* out = (float*)d_out;

    float* wsf      = (float*)d_ws;
    float* lossrow  = wsf;              // N floats
    float* sq       = wsf + N;          // N floats
    float* dot0     = wsf + 2 * N;      // N floats
    unsigned* cnt   = (unsigned*)(wsf + 3 * N); // N uints

    hipMemsetAsync(cnt, 0, N * sizeof(unsigned), stream);

    prep_kernel<<<N, 256, 0, stream>>>(x, sq, dot0);
    ce_kernel<<<N, 128, 0, stream>>>(x, y, W, b, lossrow);
    count_kernel<<<(N / TI) * (N / TI), 256, 0, stream>>>(x, sq, dot0, cnt);
    final_kernel<<<1, 256, 0, stream>>>(lossrow, cnt, y, Y, out);
}

// Round 2
// 142.155 us; speedup vs baseline: 2.7675x; 2.7675x over previous
//
#include <hip/hip_runtime.h>
#include <math.h>
#include <stdint.h>

#define N 4096
#define D 512
#define C 128
#define ALPHA 0.0005f

typedef __bf16 bf16x8 __attribute__((ext_vector_type(8)));
typedef float f32x4 __attribute__((ext_vector_type(4)));

// async global->LDS, 16B per lane. LDS dest must be wave-uniform base + lane*16.
__device__ __forceinline__ void async16(const void* g, void* l) {
    __builtin_amdgcn_global_load_lds(
        reinterpret_cast<const __attribute__((address_space(1))) uint32_t*>(
            reinterpret_cast<uintptr_t>(g)),
        reinterpret_cast<__attribute__((address_space(3))) uint32_t*>(
            reinterpret_cast<uintptr_t>(l)),
        16, 0, 0);
}

// ---------------------------------------------------------------------------
// prep: sq[i] = ||x_i||^2 ; dot0[i] = x_i . x_0 ; xb = bf16(x)
// ---------------------------------------------------------------------------
__global__ __launch_bounds__(256) void prep_kernel(const float* __restrict__ x,
                                                   float* __restrict__ sq,
                                                   float* __restrict__ dot0,
                                                   __bf16* __restrict__ xb) {
    const int i = blockIdx.x;
    const int t = threadIdx.x;
    float s1 = 0.f, s2 = 0.f;
    for (int k = t; k < D; k += 256) {
        float v = x[(size_t)i * D + k];
        xb[(size_t)i * D + k] = (__bf16)v;
        s1 += v * v;
        s2 += v * x[k];           // x[0,k]
    }
    for (int o = 32; o; o >>= 1) {
        s1 += __shfl_down(s1, o);
        s2 += __shfl_down(s2, o);
    }
    __shared__ float r1[4], r2[4];
    if ((t & 63) == 0) { r1[t >> 6] = s1; r2[t >> 6] = s2; }
    __syncthreads();
    if (t == 0) {
        sq[i]   = r1[0] + r1[1] + r1[2] + r1[3];
        dot0[i] = r2[0] + r2[1] + r2[2] + r2[3];
    }
}

// ---------------------------------------------------------------------------
// wconv: Wtb[n][k] = bf16(W[k][n])   (C x D, k-contiguous for B-frag reads)
// ---------------------------------------------------------------------------
__global__ __launch_bounds__(256) void wconv_kernel(const float* __restrict__ W,
                                                    __bf16* __restrict__ Wtb) {
    const int tid = blockIdx.x * 256 + threadIdx.x;   // 0 .. D*C-1
    const int k = tid >> 7;      // D index
    const int n = tid & 127;     // C index
    Wtb[(size_t)n * D + k] = (__bf16)W[tid];
}

// ---------------------------------------------------------------------------
// ce_mfma: logits = xb @ Wtb^T + b, row-wise log-softmax, pick col y[i].
// 32 blocks x 128 rows. 4 waves 2x2, each wave 64x64 via 4x4 MFMA 16x16x32.
// ---------------------------------------------------------------------------
__global__ __launch_bounds__(256) void ce_mfma(const __bf16* __restrict__ xb,
                                               const __bf16* __restrict__ Wtb,
                                               const int* __restrict__ y,
                                               const float* __restrict__ b,
                                               float* __restrict__ lossrow) {
    __shared__ __bf16 Alds[128 * 32];
    __shared__ __bf16 Blds[128 * 32];
    __shared__ float rmax[128][2];
    __shared__ float rsum[128][2];
    const int t = threadIdx.x;
    const int bi = blockIdx.x * 128;
    const int w = t >> 6, l = t & 63;
    const int wy = w >> 1, wx = w & 1;
    const int kg = l >> 4, lr = l & 15;

    f32x4 acc[4][4];
    const f32x4 zero = {0.f, 0.f, 0.f, 0.f};
#pragma unroll
    for (int mt = 0; mt < 4; ++mt)
#pragma unroll
        for (int nt = 0; nt < 4; ++nt) acc[mt][nt] = zero;

    const int e0 = t, e1 = t + 256;
    const int ar0 = e0 >> 2, ac0 = (e0 & 3) * 8;
    const int ar1 = e1 >> 2, ac1 = (e1 & 3) * 8;

    for (int kc = 0; kc < D; kc += 32) {
        __syncthreads();
        async16(xb  + (size_t)(bi + ar0) * D + kc + ac0, (char*)Alds + e0 * 16);
        async16(xb  + (size_t)(bi + ar1) * D + kc + ac1, (char*)Alds + e1 * 16);
        async16(Wtb + (size_t)ar0 * D + kc + ac0,        (char*)Blds + e0 * 16);
        async16(Wtb + (size_t)ar1 * D + kc + ac1,        (char*)Blds + e1 * 16);
        __syncthreads();
        bf16x8 av[4], bv[4];
#pragma unroll
        for (int mt = 0; mt < 4; ++mt)
            av[mt] = *(const bf16x8*)(Alds + (wy * 64 + mt * 16 + lr) * 32 + kg * 8);
#pragma unroll
        for (int nt = 0; nt < 4; ++nt)
            bv[nt] = *(const bf16x8*)(Blds + (wx * 64 + nt * 16 + lr) * 32 + kg * 8);
#pragma unroll
        for (int mt = 0; mt < 4; ++mt)
#pragma unroll
            for (int nt = 0; nt < 4; ++nt)
                acc[mt][nt] = __builtin_amdgcn_mfma_f32_16x16x32_bf16(av[mt], bv[nt], acc[mt][nt], 0, 0, 0);
    }

    // epilogue: log-softmax over 128 cols (2 wx halves), write lossrow.
    int jn[4]; float bb[4];
#pragma unroll
    for (int nt = 0; nt < 4; ++nt) { jn[nt] = wx * 64 + nt * 16 + lr; bb[nt] = b[jn[nt]]; }

#pragma unroll
    for (int mt = 0; mt < 4; ++mt)
#pragma unroll
        for (int r = 0; r < 4; ++r) {
            float m = acc[mt][0][r] + bb[0];
#pragma unroll
            for (int nt = 1; nt < 4; ++nt) m = fmaxf(m, acc[mt][nt][r] + bb[nt]);
            m = fmaxf(m, __shfl_xor(m, 1));
            m = fmaxf(m, __shfl_xor(m, 2));
            m = fmaxf(m, __shfl_xor(m, 4));
            m = fmaxf(m, __shfl_xor(m, 8));
            if (lr == 0) rmax[wy * 64 + mt * 16 + kg * 4 + r][wx] = m;
        }
    __syncthreads();
    float mrow[4][4];
#pragma unroll
    for (int mt = 0; mt < 4; ++mt)
#pragma unroll
        for (int r = 0; r < 4; ++r) {
            const int ri = wy * 64 + mt * 16 + kg * 4 + r;
            mrow[mt][r] = fmaxf(rmax[ri][0], rmax[ri][1]);
            float s = 0.f;
#pragma unroll
            for (int nt = 0; nt < 4; ++nt) s += expf(acc[mt][nt][r] + bb[nt] - mrow[mt][r]);
            s += __shfl_xor(s, 1);
            s += __shfl_xor(s, 2);
            s += __shfl_xor(s, 4);
            s += __shfl_xor(s, 8);
            if (lr == 0) rsum[ri][wx] = s;
        }
    __syncthreads();
#pragma unroll
    for (int mt = 0; mt < 4; ++mt)
#pragma unroll
        for (int r = 0; r < 4; ++r) {
            const int ri = wy * 64 + mt * 16 + kg * 4 + r;
            const int i = bi + ri;
            const float s = rsum[ri][0] + rsum[ri][1];
            const int yi = y[i];
#pragma unroll
            for (int nt = 0; nt < 4; ++nt)
                if (jn[nt] == yi)
                    lossrow[i] = -(acc[mt][nt][r] + bb[nt] - mrow[mt][r] - logf(s));
        }
}

// ---------------------------------------------------------------------------
// count_mfma: cnt[i] += #{ j in block cols, j!=i, j!=0 :
//                          sq[j] - 2*dot(x_i,x_j) < sq[0] - 2*dot0[i] }
// 1024 blocks of 128x128. Same MFMA structure as ce_mfma.
// ---------------------------------------------------------------------------
__global__ __launch_bounds__(256) void count_mfma(const __bf16* __restrict__ xb,
                                                  const float* __restrict__ sq,
                                                  const float* __restrict__ dot0,
                                                  unsigned* __restrict__ cnt) {
    __shared__ __bf16 Alds[128 * 32];
    __shared__ __bf16 Blds[128 * 32];
    const int t = threadIdx.x;
    const int bi = (int)(blockIdx.x & 31) * 128;
    const int bj = (int)(blockIdx.x >> 5) * 128;
    const int w = t >> 6, l = t & 63;
    const int wy = w >> 1, wx = w & 1;
    const int kg = l >> 4, lr = l & 15;

    f32x4 acc[4][4];
    const f32x4 zero = {0.f, 0.f, 0.f, 0.f};
#pragma unroll
    for (int mt = 0; mt < 4; ++mt)
#pragma unroll
        for (int nt = 0; nt < 4; ++nt) acc[mt][nt] = zero;

    const int e0 = t, e1 = t + 256;
    const int ar0 = e0 >> 2, ac0 = (e0 & 3) * 8;
    const int ar1 = e1 >> 2, ac1 = (e1 & 3) * 8;

    for (int kc = 0; kc < D; kc += 32) {
        __syncthreads();
        async16(xb + (size_t)(bi + ar0) * D + kc + ac0, (char*)Alds + e0 * 16);
        async16(xb + (size_t)(bi + ar1) * D + kc + ac1, (char*)Alds + e1 * 16);
        async16(xb + (size_t)(bj + ar0) * D + kc + ac0, (char*)Blds + e0 * 16);
        async16(xb + (size_t)(bj + ar1) * D + kc + ac1, (char*)Blds + e1 * 16);
        __syncthreads();
        bf16x8 av[4], bv[4];
#pragma unroll
        for (int mt = 0; mt < 4; ++mt)
            av[mt] = *(const bf16x8*)(Alds + (wy * 64 + mt * 16 + lr) * 32 + kg * 8);
#pragma unroll
        for (int nt = 0; nt < 4; ++nt)
            bv[nt] = *(const bf16x8*)(Blds + (wx * 64 + nt * 16 + lr) * 32 + kg * 8);
#pragma unroll
        for (int mt = 0; mt < 4; ++mt)
#pragma unroll
            for (int nt = 0; nt < 4; ++nt)
                acc[mt][nt] = __builtin_amdgcn_mfma_f32_16x16x32_bf16(av[mt], bv[nt], acc[mt][nt], 0, 0, 0);
    }

    // epilogue: comparison + per-row count
    const float sq0 = sq[0];
    int jn[4]; float sqj[4];
#pragma unroll
    for (int nt = 0; nt < 4; ++nt) {
        jn[nt] = bj + wx * 64 + nt * 16 + lr;
        sqj[nt] = sq[jn[nt]];
    }
#pragma unroll
    for (int mt = 0; mt < 4; ++mt)
#pragma unroll
        for (int r = 0; r < 4; ++r) {
            const int i = bi + wy * 64 + mt * 16 + kg * 4 + r;
            const float ti = sq0 - 2.0f * dot0[i];
            unsigned c = 0;
#pragma unroll
            for (int nt = 0; nt < 4; ++nt) {
                const float lhs = sqj[nt] - 2.0f * acc[mt][nt][r];
                if (lhs < ti && jn[nt] != i && jn[nt] != 0) ++c;
            }
            c += __shfl_xor((int)c, 1);
            c += __shfl_xor((int)c, 2);
            c += __shfl_xor((int)c, 4);
            c += __shfl_xor((int)c, 8);
            if (lr == 0 && c) atomicAdd(&cnt[i], c);
        }
}

// ---------------------------------------------------------------------------
// finalize: out = mean(lossrow) + ALPHA * sum_{i>0, y_i==y_0, cnt[i]<=1} ||Y_i - Y_0||
// ---------------------------------------------------------------------------
__global__ __launch_bounds__(256) void final_kernel(const float* __restrict__ lossrow,
                                                    const unsigned* __restrict__ cnt,
                                                    const int* __restrict__ y,
                                                    const float* __restrict__ Y,
                                                    float* __restrict__ out) {
    const int t = threadIdx.x;
    const int y0 = y[0];
    double ls = 0.0, rs = 0.0;
    for (int i = t; i < N; i += 256) {
        ls += (double)lossrow[i];
        if (i > 0 && y[i] == y0 && cnt[i] <= 1u) {
            float d2 = 0.f;
            for (int c = 0; c < C; ++c) {
                float d = Y[(size_t)i * C + c] - Y[c];
                d2 += d * d;
            }
            rs += (double)sqrtf(fmaxf(d2, 0.f));
        }
    }
    for (int o = 32; o; o >>= 1) {
        ls += __shfl_down(ls, o);
        rs += __shfl_down(rs, o);
    }
    __shared__ double dl[4], dr[4];
    if ((t & 63) == 0) { dl[t >> 6] = ls; dr[t >> 6] = rs; }
    __syncthreads();
    if (t == 0) {
        double L = (dl[0] + dl[1] + dl[2] + dl[3]) / (double)N;
        double R = (dr[0] + dr[1] + dr[2] + dr[3]);
        out[0] = (float)(L + (double)ALPHA * R);
    }
}

// ---------------------------------------------------------------------------
extern "C" void kernel_launch(void* const* d_in, const int* in_sizes, int n_in,
                              void* d_out, int out_size, void* d_ws, size_t ws_size,
                              hipStream_t stream) {
    const float* x  = (const float*)d_in[0];   // (N, D)
    const int*   y  = (const int*)d_in[1];     // (N,)
    const float* Y  = (const float*)d_in[2];   // (N, C)
    const float* W  = (const float*)d_in[3];   // (D, C)
    const float* b  = (const float*)d_in[4];   // (C,)
    float* out = (float*)d_out;

    float* wsf      = (float*)d_ws;
    float* lossrow  = wsf;                       // N f32
    float* sq       = wsf + N;                   // N f32
    float* dot0     = wsf + 2 * N;               // N f32
    unsigned* cnt   = (unsigned*)(wsf + 3 * N);  // N u32
    __bf16* xb      = (__bf16*)(wsf + 4 * N);        // N*D bf16 (4 MB)
    __bf16* Wtb     = (__bf16*)((char*)xb + (size_t)N * D * 2); // C*D bf16 (128 KB)

    hipMemsetAsync(cnt, 0, N * sizeof(unsigned), stream);

    prep_kernel<<<N, 256, 0, stream>>>(x, sq, dot0, xb);
    wconv_kernel<<<(D * C) / 256, 256, 0, stream>>>(W, Wtb);
    ce_mfma<<<N / 128, 256, 0, stream>>>(xb, Wtb, y, b, lossrow);
    count_mfma<<<(N / 128) * (N / 128), 256, 0, stream>>>(xb, sq, dot0, cnt);
    final_kernel<<<1, 256, 0, stream>>>(lossrow, cnt, y, Y, out);
}

// Round 3
// 117.330 us; speedup vs baseline: 3.3531x; 1.2116x over previous
//
#include <hip/hip_runtime.h>
#include <math.h>
#include <stdint.h>

#define N 4096
#define D 512
#define C 128
#define ALPHA 0.0005f
#define NT_TILES 32                 // N/128
#define TRI (NT_TILES * (NT_TILES + 1) / 2)   // 528 count tiles

typedef __bf16 bf16x8 __attribute__((ext_vector_type(8)));
typedef float f32x4 __attribute__((ext_vector_type(4)));

// async global->LDS, 16B per lane. LDS dest must be wave-uniform base + lane*16.
__device__ __forceinline__ void async16(const void* g, void* l) {
    __builtin_amdgcn_global_load_lds(
        reinterpret_cast<const __attribute__((address_space(1))) uint32_t*>(
            reinterpret_cast<uintptr_t>(g)),
        reinterpret_cast<__attribute__((address_space(3))) uint32_t*>(
            reinterpret_cast<uintptr_t>(l)),
        16, 0, 0);
}

// ---------------------------------------------------------------------------
// prep: blocks [0,N)   : sq[i]=||x_i||^2 ; dot0[i]=x_i.x_0 ; xb=bf16(x)
//       blocks [N,N+256): Wtb[n][k] = bf16(W[k][n])
// ---------------------------------------------------------------------------
__global__ __launch_bounds__(256) void prep_kernel(const float* __restrict__ x,
                                                   float* __restrict__ sq,
                                                   float* __restrict__ dot0,
                                                   __bf16* __restrict__ xb,
                                                   const float* __restrict__ W,
                                                   __bf16* __restrict__ Wtb) {
    if (blockIdx.x >= N) {
        const int tid = (blockIdx.x - N) * 256 + threadIdx.x;  // 0..D*C-1
        const int k = tid >> 7;
        const int n = tid & 127;
        Wtb[(size_t)n * D + k] = (__bf16)W[tid];
        return;
    }
    const int i = blockIdx.x;
    const int t = threadIdx.x;
    float s1 = 0.f, s2 = 0.f;
    for (int k = t; k < D; k += 256) {
        float v = x[(size_t)i * D + k];
        xb[(size_t)i * D + k] = (__bf16)v;
        s1 += v * v;
        s2 += v * x[k];           // x[0,k]
    }
    for (int o = 32; o; o >>= 1) {
        s1 += __shfl_down(s1, o);
        s2 += __shfl_down(s2, o);
    }
    __shared__ float r1[4], r2[4];
    if ((t & 63) == 0) { r1[t >> 6] = s1; r2[t >> 6] = s2; }
    __syncthreads();
    if (t == 0) {
        sq[i]   = r1[0] + r1[1] + r1[2] + r1[3];
        dot0[i] = r2[0] + r2[1] + r2[2] + r2[3];
    }
}

// ---------------------------------------------------------------------------
// fused_mfma:
//   blocks [0,TRI)      : neighbor-count tile (ti,tj), tj>=ti, symmetric update
//   blocks [TRI,TRI+32) : CE tile (128 rows x 128 logits + log-softmax)
// 128x128 tile, BK=64, 4 waves 2x2, 4x4 frags of mfma_f32_16x16x32_bf16.
// LDS slot XOR-swizzle (source-side) keeps global loads coalesced AND frag
// ds_read_b128 conflict-free.
// ---------------------------------------------------------------------------
__global__ __launch_bounds__(256) void fused_mfma(const __bf16* __restrict__ xb,
                                                  const __bf16* __restrict__ Wtb,
                                                  const float* __restrict__ sq,
                                                  const float* __restrict__ dot0,
                                                  const int* __restrict__ y,
                                                  const float* __restrict__ b,
                                                  unsigned* __restrict__ cnt,
                                                  float* __restrict__ lossrow) {
    __shared__ __bf16 Alds[128 * 64];
    __shared__ __bf16 Blds[128 * 64];
    __shared__ float rmax[128][2];
    __shared__ float rsum[128][2];
    const int t = threadIdx.x;
    const int w = t >> 6, l = t & 63;
    const int wy = w >> 1, wx = w & 1;
    const int kg = l >> 4, lr = l & 15;

    const int bid = (int)blockIdx.x;
    const bool isCE = (bid >= TRI);
    int bi, bj;
    bool diag = false;
    const __bf16* Bbase;
    if (isCE) {
        bi = (bid - TRI) * 128;
        bj = 0;
        Bbase = Wtb;
    } else {
        int tj = (int)((sqrtf(8.f * (float)bid + 1.f) - 1.f) * 0.5f);
        while (tj * (tj + 1) / 2 > bid) --tj;
        while ((tj + 1) * (tj + 2) / 2 <= bid) ++tj;
        const int ti = bid - tj * (tj + 1) / 2;
        bi = ti * 128;
        bj = tj * 128;
        diag = (ti == tj);
        Bbase = xb + (size_t)bj * D;
    }
    const __bf16* Abase = xb + (size_t)bi * D;

    f32x4 acc[4][4];
    const f32x4 zero = {0.f, 0.f, 0.f, 0.f};
#pragma unroll
    for (int mt = 0; mt < 4; ++mt)
#pragma unroll
        for (int nt = 0; nt < 4; ++nt) acc[mt][nt] = zero;

    for (int kc = 0; kc < D; kc += 64) {
        __syncthreads();
#pragma unroll
        for (int s = 0; s < 4; ++s) {
            const int e = t + 256 * s;          // 0..1023
            const int r = e >> 3;               // tile row 0..127
            const int c = e & 7;                // LDS slot (8 bf16 = 16 B)
            const int sc = c ^ (r & 7);         // swizzled source col-group
            async16(Abase + (size_t)r * D + kc + sc * 8, (char*)Alds + e * 16);
            if (!diag)
                async16(Bbase + (size_t)r * D + kc + sc * 8, (char*)Blds + e * 16);
        }
        __syncthreads();
        const __bf16* Bl = diag ? Alds : Blds;
#pragma unroll
        for (int kk = 0; kk < 2; ++kk) {
            bf16x8 av[4], bv[4];
#pragma unroll
            for (int mt = 0; mt < 4; ++mt) {
                const int row = wy * 64 + mt * 16 + lr;
                const int slot = (kk * 4 + kg) ^ (row & 7);
                av[mt] = *(const bf16x8*)(Alds + row * 64 + slot * 8);
            }
#pragma unroll
            for (int nt = 0; nt < 4; ++nt) {
                const int row = wx * 64 + nt * 16 + lr;
                const int slot = (kk * 4 + kg) ^ (row & 7);
                bv[nt] = *(const bf16x8*)(Bl + row * 64 + slot * 8);
            }
#pragma unroll
            for (int mt = 0; mt < 4; ++mt)
#pragma unroll
                for (int nt = 0; nt < 4; ++nt)
                    acc[mt][nt] = __builtin_amdgcn_mfma_f32_16x16x32_bf16(av[mt], bv[nt], acc[mt][nt], 0, 0, 0);
        }
    }

    if (isCE) {
        // ---- CE epilogue: log-softmax over 128 cols, pick col y[i] ----
        int jn[4]; float bb[4];
#pragma unroll
        for (int nt = 0; nt < 4; ++nt) { jn[nt] = wx * 64 + nt * 16 + lr; bb[nt] = b[jn[nt]]; }
#pragma unroll
        for (int mt = 0; mt < 4; ++mt)
#pragma unroll
            for (int r = 0; r < 4; ++r) {
                float m = acc[mt][0][r] + bb[0];
#pragma unroll
                for (int nt = 1; nt < 4; ++nt) m = fmaxf(m, acc[mt][nt][r] + bb[nt]);
                m = fmaxf(m, __shfl_xor(m, 1));
                m = fmaxf(m, __shfl_xor(m, 2));
                m = fmaxf(m, __shfl_xor(m, 4));
                m = fmaxf(m, __shfl_xor(m, 8));
                if (lr == 0) rmax[wy * 64 + mt * 16 + kg * 4 + r][wx] = m;
            }
        __syncthreads();
        float mrow[4][4];
#pragma unroll
        for (int mt = 0; mt < 4; ++mt)
#pragma unroll
            for (int r = 0; r < 4; ++r) {
                const int ri = wy * 64 + mt * 16 + kg * 4 + r;
                mrow[mt][r] = fmaxf(rmax[ri][0], rmax[ri][1]);
                float s = 0.f;
#pragma unroll
                for (int nt = 0; nt < 4; ++nt) s += expf(acc[mt][nt][r] + bb[nt] - mrow[mt][r]);
                s += __shfl_xor(s, 1);
                s += __shfl_xor(s, 2);
                s += __shfl_xor(s, 4);
                s += __shfl_xor(s, 8);
                if (lr == 0) rsum[ri][wx] = s;
            }
        __syncthreads();
#pragma unroll
        for (int mt = 0; mt < 4; ++mt)
#pragma unroll
            for (int r = 0; r < 4; ++r) {
                const int ri = wy * 64 + mt * 16 + kg * 4 + r;
                const int i = bi + ri;
                const float s = rsum[ri][0] + rsum[ri][1];
                const int yi = y[i];
#pragma unroll
                for (int nt = 0; nt < 4; ++nt)
                    if (jn[nt] == yi)
                        lossrow[i] = -(acc[mt][nt][r] + bb[nt] - mrow[mt][r] - logf(s));
            }
    } else {
        // ---- count epilogue (symmetric) ----
        const float sq0 = sq[0];
        int jn[4]; float sqj[4], thrj[4];
#pragma unroll
        for (int nt = 0; nt < 4; ++nt) {
            jn[nt] = bj + wx * 64 + nt * 16 + lr;
            sqj[nt] = sq[jn[nt]];
            thrj[nt] = sq0 - 2.0f * dot0[jn[nt]];
        }
        unsigned cj[4] = {0u, 0u, 0u, 0u};
#pragma unroll
        for (int mt = 0; mt < 4; ++mt)
#pragma unroll
            for (int r = 0; r < 4; ++r) {
                const int i = bi + wy * 64 + mt * 16 + kg * 4 + r;
                const float thri = sq0 - 2.0f * dot0[i];
                const float sqi = sq[i];
                unsigned ci = 0;
                if (diag) {
#pragma unroll
                    for (int nt = 0; nt < 4; ++nt) {
                        const float d = acc[mt][nt][r];
                        const int j = jn[nt];
                        if (sqj[nt] - 2.0f * d < thri && j != i && j != 0) ++ci;
                    }
                } else {
                    // bj > bi: j >= 128 > 0 and i < bj <= j, no guards needed
#pragma unroll
                    for (int nt = 0; nt < 4; ++nt) {
                        const float d = acc[mt][nt][r];
                        if (sqj[nt] - 2.0f * d < thri) ++ci;
                        if (sqi - 2.0f * d < thrj[nt] && i != 0) ++cj[nt];
                    }
                }
                ci += __shfl_xor((int)ci, 1);
                ci += __shfl_xor((int)ci, 2);
                ci += __shfl_xor((int)ci, 4);
                ci += __shfl_xor((int)ci, 8);
                if (lr == 0 && ci) atomicAdd(&cnt[i], ci);
            }
        if (!diag) {
#pragma unroll
            for (int nt = 0; nt < 4; ++nt) {
                unsigned v = cj[nt];
                v += __shfl_xor((int)v, 16);
                v += __shfl_xor((int)v, 32);
                if (l < 16 && v) atomicAdd(&cnt[jn[nt]], v);
            }
        }
    }
}

// ---------------------------------------------------------------------------
// finalize: out = mean(lossrow) + ALPHA * sum_{i>0, y_i==y_0, cnt[i]<=1} ||Y_i - Y_0||
// ---------------------------------------------------------------------------
__global__ __launch_bounds__(256) void final_kernel(const float* __restrict__ lossrow,
                                                    const unsigned* __restrict__ cnt,
                                                    const int* __restrict__ y,
                                                    const float* __restrict__ Y,
                                                    float* __restrict__ out) {
    const int t = threadIdx.x;
    const int y0 = y[0];
    double ls = 0.0, rs = 0.0;
    for (int i = t; i < N; i += 256) {
        ls += (double)lossrow[i];
        if (i > 0 && y[i] == y0 && cnt[i] <= 1u) {
            float d2 = 0.f;
            for (int c = 0; c < C; ++c) {
                float d = Y[(size_t)i * C + c] - Y[c];
                d2 += d * d;
            }
            rs += (double)sqrtf(fmaxf(d2, 0.f));
        }
    }
    for (int o = 32; o; o >>= 1) {
        ls += __shfl_down(ls, o);
        rs += __shfl_down(rs, o);
    }
    __shared__ double dl[4], dr[4];
    if ((t & 63) == 0) { dl[t >> 6] = ls; dr[t >> 6] = rs; }
    __syncthreads();
    if (t == 0) {
        double L = (dl[0] + dl[1] + dl[2] + dl[3]) / (double)N;
        double R = (dr[0] + dr[1] + dr[2] + dr[3]);
        out[0] = (float)(L + (double)ALPHA * R);
    }
}

// ---------------------------------------------------------------------------
extern "C" void kernel_launch(void* const* d_in, const int* in_sizes, int n_in,
                              void* d_out, int out_size, void* d_ws, size_t ws_size,
                              hipStream_t stream) {
    const float* x  = (const float*)d_in[0];   // (N, D)
    const int*   y  = (const int*)d_in[1];     // (N,)
    const float* Y  = (const float*)d_in[2];   // (N, C)
    const float* W  = (const float*)d_in[3];   // (D, C)
    const float* b  = (const float*)d_in[4];   // (C,)
    float* out = (float*)d_out;

    float* wsf      = (float*)d_ws;
    float* lossrow  = wsf;                       // N f32
    float* sq       = wsf + N;                   // N f32
    float* dot0     = wsf + 2 * N;               // N f32
    unsigned* cnt   = (unsigned*)(wsf + 3 * N);  // N u32
    __bf16* xb      = (__bf16*)(wsf + 4 * N);    // N*D bf16 (4 MB)
    __bf16* Wtb     = (__bf16*)((char*)xb + (size_t)N * D * 2); // C*D bf16

    hipMemsetAsync(cnt, 0, N * sizeof(unsigned), stream);

    prep_kernel<<<N + (D * C) / 256, 256, 0, stream>>>(x, sq, dot0, xb, W, Wtb);
    fused_mfma<<<TRI + N / 128, 256, 0, stream>>>(xb, Wtb, sq, dot0, y, b, cnt, lossrow);
    final_kernel<<<1, 256, 0, stream>>>(lossrow, cnt, y, Y, out);
}